// Round 13
// baseline (51.648 us; speedup 1.0000x reference)
//
#include <hip/hip_runtime.h>

// Not-a-knot cubic spline upsample (512 x 8192 f32 -> 512 x 32768 f32).
//
// Single-barrier-per-tile pipelined schedule (T3-style): each window runs
//   EVAL(k)   : ds_read Cc[cur] + VMEM stores
//   CONV(k+1) : ds_read ys[nxt] + VALU + ds_write Cc[nxt]
//   stage     : ds_write ys[cur] = regA (tile k+2), issue load tile k+3
// concurrently (full dbuf on ys AND Cc makes the window race-free), then ONE
// __syncthreads. R12 did [stage+conv] bar [eval] bar -> pipes serialized
// (R5's "sum of phases"); cuts to VALU/LDS/conflicts (R11/R12) moved nothing,
// isolating phase structure as the residual cost.
//
// Boundary handling is PER-THREAD now (no bt/Mtmp LDS, no special tiles):
// threads whose seed anchor A = s0+4*tid is outside [8, 8179] compute their
// 5 knots' M via the reflected-RHS global-read path (R1/R10-proven).
// Conv core (K=8 seeds + 3 recurrences), eval core (select-free u0/u3,
// exact integer t), LOAD, dense stores: verbatim R12 (absmax 0.03125).

typedef float f32x4 __attribute__((ext_vector_type(4)));

constexpr int W    = 8192;
constexpr int WU   = 32768;
constexpr int TILE = 512;
constexpr int TPB  = 4;
constexpr int HL   = 16;
constexpr int YSL  = 145;            // 136 slots + (s>>4) skew
constexpr int CCN  = 546;            // 513 slots + (s>>4) skew

constexpr float Rr  = -0.26794919243112270647f;  // sqrt(3)-2
constexpr float W0c = -4.39230484541326386f;     // 12C(r-1)
constexpr float W1c =  2.78460969082652752f;     // 6C(1-r)^2
constexpr float Cg  =  0.288675134594812882f;    // C = 1/(2 sqrt(3))

__device__ __forceinline__ int skw(int s) { return s + (s >> 4); }

__device__ __forceinline__ float convg(const float* __restrict__ xr, int j,
                                       float M1g, float Mn2g) {
    // b-space Green conv with odd reflection about -1 and n, K=10 (R1-proven).
    const int n = W - 4;
    auto bg = [&](int m) -> float {
        if (m == -1 || m == n) return 0.f;
        float sgn = 1.f;
        if (m < -1)      { m = -2 - m;   sgn = -1.f; }
        else if (m > n)  { m = 2*n - m;  sgn = -1.f; }
        int p = m + 2;
        float v = 6.f * (xr[p+1] - 2.f*xr[p] + xr[p-1]);
        if (m == 0)     v -= M1g;
        if (m == n - 1) v -= Mn2g;
        return sgn * v;
    };
    const int mc = j - 2;
    float acc = Cg * bg(mc);
    float wr  = Cg;
    #pragma unroll
    for (int d = 1; d <= 10; ++d) {
        wr  *= Rr;
        acc += wr * (bg(mc - d) + bg(mc + d));
    }
    return acc;
}

__global__ __launch_bounds__(256)
void spline_kernel(const float* __restrict__ x, float* __restrict__ out)
{
    const int row = blockIdx.y;
    const int t0  = blockIdx.x * TPB;
    const int tid = threadIdx.x;

    const float* __restrict__ xr   = x   + (size_t)row * W;
    float*       __restrict__ orow = out + (size_t)row * WU;

    __shared__ __align__(16) f32x4 ys4[2][YSL];
    __shared__ __align__(16) f32x4 Cc[2][CCN];

    auto LOAD = [&](int tile) -> f32x4 {
        f32x4 v = {0.f, 0.f, 0.f, 0.f};
        if (tid < 136) {
            int base = tile * TILE - HL + 4 * tid;
            if (tile == 0 || tile == 15) {
                #pragma unroll
                for (int e = 0; e < 4; ++e) {
                    int g = base + e;
                    g = g < 0 ? 0 : (g > W - 1 ? W - 1 : g);
                    v[e] = xr[g];
                }
            } else {
                v = *(const f32x4*)(xr + base);
            }
        }
        return v;
    };

    auto CONV = [&](int tile, int rb, int wb) {
        if (tid >= 129) return;
        const int s0 = tile * TILE;
        const int A  = s0 + 4 * tid;            // seed anchor knot
        const int nc = (tid == 128) ? 1 : 4;
        if (A >= 8 && A <= 8179) {
            // fast: K=8 seeds + 3 recurrences (R12-proven)
            const f32x4* ysc = ys4[rb];
            float w[20];                         // w[m] = y[A-8+m]
            #pragma unroll
            for (int kk = 0; kk < 5; ++kk) {
                f32x4 v = ysc[skw(tid + 2 + kk)];
                w[4*kk+0]=v.x; w[4*kk+1]=v.y; w[4*kk+2]=v.z; w[4*kk+3]=v.w;
            }
            float m1 = W0c * w[8], m2 = W0c * w[9];
            float wd = W1c;
            #pragma unroll
            for (int d = 1; d <= 8; ++d) {
                m1 += wd * (w[8 - d] + w[8 + d]);
                m2 += wd * (w[9 - d] + w[9 + d]);
                wd *= Rr;                        // folds to literals
            }
            float a[5];                          // a[d] = M[A-1+d]
            a[1] = m1; a[2] = m2;
            a[0] = 6.f*(w[9]  - 2.f*w[8]  + w[7]) - 4.f*m1   - m2;
            a[3] = 6.f*(w[10] - 2.f*w[9]  + w[8]) - 4.f*m2   - m1;
            a[4] = 6.f*(w[11] - 2.f*w[10] + w[9]) - 4.f*a[3] - m2;
            #pragma unroll
            for (int c = 0; c < 4; ++c) if (c < nc) {
                float y0 = w[7 + c], y1 = w[8 + c];
                Cc[wb][skw(4*tid + c)] =
                    (f32x4){y0, (y1 - y0) - (2.f*a[c] + a[c+1]) * (1.f/6.f),
                            0.5f * a[c], (a[c+1] - a[c]) * (1.f/6.f)};
            }
        } else {
            // slow: reflected-RHS via global reads (R1/R10-proven); ~6/row
            float M1g  = xr[0]   - 2.f*xr[1]   + xr[2];
            float Mn2g = xr[W-1] - 2.f*xr[W-2] + xr[W-3];
            float Y[5], Mv[5];
            #pragma unroll
            for (int d = 0; d < 5; ++d) {
                int j = A - 1 + d;
                j = j < 0 ? 0 : (j > W - 1 ? W - 1 : j);   // clamp: degenerate
                Y[d] = xr[j];                              //  intervals exact
                float m;                                   //  at their t=1/t=0
                if (j == 0)        m = 2.f*M1g  - convg(xr, 2,   M1g, Mn2g);
                else if (j == 1)   m = M1g;
                else if (j == W-2) m = Mn2g;
                else if (j == W-1) m = 2.f*Mn2g - convg(xr, W-3, M1g, Mn2g);
                else               m = convg(xr, j, M1g, Mn2g);
                Mv[d] = m;
            }
            #pragma unroll
            for (int c = 0; c < 4; ++c) if (c < nc) {
                Cc[wb][skw(4*tid + c)] =
                    (f32x4){Y[c], (Y[c+1]-Y[c]) - (2.f*Mv[c]+Mv[c+1])*(1.f/6.f),
                            0.5f*Mv[c], (Mv[c+1]-Mv[c]) * (1.f/6.f)};
            }
        }
    };

    auto EVAL = [&](int tile, int cb) {
        const int s0 = tile * TILE;
        constexpr float inv = 1.f / 32767.f;
        #pragma unroll
        for (int it = 0; it < 2; ++it) {
            const int j = tid + 256 * it;        // quad h = s0+j; q0 = 4h
            const int h = s0 + j;
            const int e = 32767 - 3 * h;
            f32x4 cA = Cc[cb][skw(j)];
            f32x4 cB = Cc[cb][skw(j + 1)];
            const int N1 = e + 8191, N2 = e + 16382;
            const bool c1 = N1 >= 32767, c2 = N2 >= 32767;
            float tq0 = (float)e * inv;          // h=0: t=1 on degenerate
            float tq1 = (float)(c1 ? N1 - 32767 : N1) * inv;
            float tq2 = (float)(c2 ? N2 - 32767 : N2) * inv;
            float tq3 = (float)(e - 8194) * inv; // u=3 always crosses
            f32x4 k1 = c1 ? cB : cA;
            f32x4 k2 = c2 ? cB : cA;
            float r0 = cA.x + tq0 * (cA.y + tq0 * (cA.z + tq0 * cA.w));
            float r1 = k1.x + tq1 * (k1.y + tq1 * (k1.z + tq1 * k1.w));
            float r2 = k2.x + tq2 * (k2.y + tq2 * (k2.z + tq2 * k2.w));
            float r3 = cB.x + tq3 * (cB.y + tq3 * (cB.z + tq3 * cB.w));
            *(f32x4*)(orow + 4 * h) = (f32x4){r0, r1, r2, r3};
        }
    };

    // ---- prologue: both initial loads in flight, then fill ys[0], ys[1] ----
    f32x4 a0 = LOAD(t0);
    f32x4 a1 = LOAD(t0 + 1);
    if (tid < 136) ys4[0][skw(tid)] = a0;
    __syncthreads();                             // ys[0] ready
    CONV(t0, 0, 0);                              // Cc[0] = tile t0
    if (tid < 136) ys4[1][skw(tid)] = a1;        // tile t0+1 -> ys[1]
    f32x4 regA = LOAD(t0 + 2);
    __syncthreads();                             // Cc[0], ys[1] ready

    // ---- main: one barrier per tile; all pipes live in every window ----
    for (int k = 0; k < TPB; ++k) {
        EVAL(t0 + k, k & 1);                     // reads Cc[cur], stores out
        if (k + 1 < TPB) CONV(t0 + k + 1, (k + 1) & 1, (k + 1) & 1);
        if (k + 2 < TPB) { if (tid < 136) ys4[k & 1][skw(tid)] = regA; }
        if (k + 3 < TPB) regA = LOAD(t0 + k + 3);
        if (k + 1 < TPB) __syncthreads();
    }
}

extern "C" void kernel_launch(void* const* d_in, const int* in_sizes, int n_in,
                              void* d_out, int out_size, void* d_ws, size_t ws_size,
                              hipStream_t stream) {
    const float* x = (const float*)d_in[0];
    float* out = (float*)d_out;
    const int B = in_sizes[0] / W;               // 512 rows
    dim3 grid(W / TILE / TPB, B), block(256);    // 2048 blocks, 7/CU (LDS)
    hipLaunchKernelGGL(spline_kernel, grid, block, 0, stream, x, out);
}

// Round 14
// 45.735 us; speedup vs baseline: 1.1293x; 1.1293x over previous
//
#include <hip/hip_runtime.h>

// Not-a-knot cubic spline upsample (512 x 8192 f32 -> 512 x 32768 f32).
//
// Minimal-phase fused kernel: ONE barrier total, no intermediate LDS data.
// Thread owns anchor A (4 quads = 16 outputs q in [16A/4... 4A..4A+15]):
//   stage y[s0-8..s0+1031] dense->LDS (skew >>3, R11-proven)  | 1 barrier
//   5x ds_read_b128 window w[20] = y[A-8..A+11]
//   2 Green seeds (K=8) M[A+1],M[A+2] + 4 interior-eq recurrences
//     -> M[A-1..A+4]  (R10-proven depth/accuracy, err ~1e-2 << 0.103)
//   5 cubic coeff sets K[i] (intervals A-1..A+3) IN REGISTERS
//   16 evals, R12-proven exact integer-t logic; 4x dwordx4 plain stores
//     (R10 proved 64B/thread plain stores have no write amplification).
// Slow path (~6 threads/row: A<12 or A>8176): R10-verbatim reflected-RHS
// conv via global reads (row ends, L2-hot). Clamped degenerate intervals
// are exact at their only sampled t (0 or 1) for any M.

typedef float f32x4 __attribute__((ext_vector_type(4)));

constexpr int W   = 8192;
constexpr int WU  = 32768;
constexpr int YSL = 292;             // 260 slots + (s>>3) skew

constexpr float Rr  = -0.26794919243112270647f;  // sqrt(3)-2
constexpr float W0c = -4.39230484541326386f;     // 12C(r-1)
constexpr float W1c =  2.78460969082652752f;     // 6C(1-r)^2
constexpr float Cg  =  0.288675134594812882f;    // C = 1/(2 sqrt(3))

__device__ __forceinline__ int skw(int s) { return s + (s >> 3); }

__device__ __forceinline__ float convg(const float* __restrict__ xr, int j,
                                       float M1g, float Mn2g) {
    // b-space Green conv with odd reflection about -1 and n, K=10 (R1-proven).
    const int n = W - 4;
    auto bg = [&](int m) -> float {
        if (m == -1 || m == n) return 0.f;
        float sgn = 1.f;
        if (m < -1)      { m = -2 - m;   sgn = -1.f; }
        else if (m > n)  { m = 2*n - m;  sgn = -1.f; }
        int p = m + 2;
        float v = 6.f * (xr[p+1] - 2.f*xr[p] + xr[p-1]);
        if (m == 0)     v -= M1g;
        if (m == n - 1) v -= Mn2g;
        return sgn * v;
    };
    const int mc = j - 2;
    float acc = Cg * bg(mc);
    float wr  = Cg;
    #pragma unroll
    for (int d = 1; d <= 10; ++d) {
        wr  *= Rr;
        acc += wr * (bg(mc - d) + bg(mc + d));
    }
    return acc;
}

__global__ __launch_bounds__(256)
void spline_kernel(const float* __restrict__ x, float* __restrict__ out)
{
    const int b   = blockIdx.x;
    const int row = b >> 3;                   // 8 blocks per row
    const int bb  = b & 7;
    const int tid = threadIdx.x;
    const int s0  = bb << 10;                 // first anchor of block
    const int A   = s0 + 4 * tid;             // this thread's anchor knot

    const float* __restrict__ xr   = x   + (size_t)row * W;
    float*       __restrict__ orow = out + (size_t)row * WU;

    __shared__ __align__(16) f32x4 ys[YSL];

    // ---- stage: y[s0-8 .. s0+1031] as 260 aligned f32x4 slots ----
    {
        int gb = s0 - 8 + 4 * tid;
        f32x4 v;
        if (bb == 0 || bb == 7) {
            #pragma unroll
            for (int e = 0; e < 4; ++e) {
                int g = gb + e; g = g < 0 ? 0 : (g > W - 1 ? W - 1 : g);
                v[e] = xr[g];
            }
        } else {
            v = *(const f32x4*)(xr + gb);
        }
        ys[skw(tid)] = v;
        if (tid < 4) {
            int gb2 = s0 + 1016 + 4 * tid;
            f32x4 v2;
            if (bb == 7) {
                #pragma unroll
                for (int e = 0; e < 4; ++e) {
                    int g = gb2 + e; g = g > W - 1 ? W - 1 : g;
                    v2[e] = xr[g];
                }
            } else {
                v2 = *(const f32x4*)(xr + gb2);
            }
            ys[skw(256 + tid)] = v2;
        }
    }
    __syncthreads();                          // the ONLY barrier

    f32x4 K[5];                               // coeffs, intervals A-1..A+3
    if (A >= 12 && A <= 8176) {
        // ---- fast: window from LDS, seeds + recurrences ----
        float w[20];                          // w[m] = y[A-8+m]
        #pragma unroll
        for (int k = 0; k < 5; ++k) {
            f32x4 v = ys[skw(tid + k)];
            w[4*k+0]=v.x; w[4*k+1]=v.y; w[4*k+2]=v.z; w[4*k+3]=v.w;
        }
        float s1 = W0c * w[9], s2 = W0c * w[10];   // M[A+1], M[A+2]
        float wd = W1c;
        #pragma unroll
        for (int d = 1; d <= 8; ++d) {
            s1 += wd * (w[9  - d] + w[9  + d]);
            s2 += wd * (w[10 - d] + w[10 + d]);
            wd *= Rr;                         // folds to literals
        }
        float dA0 = 6.f*(w[9]  - 2.f*w[8]  + w[7]);   // d at knot A
        float dA1 = 6.f*(w[10] - 2.f*w[9]  + w[8]);   // A+1
        float dA2 = 6.f*(w[11] - 2.f*w[10] + w[9]);   // A+2
        float dA3 = 6.f*(w[12] - 2.f*w[11] + w[10]);  // A+3
        float a[6];                           // a[d] = M[A-1+d]
        a[2] = s1; a[3] = s2;
        a[1] = dA1 - 4.f*s1   - s2;
        a[0] = dA0 - 4.f*a[1] - s1;
        a[4] = dA2 - 4.f*s2   - s1;
        a[5] = dA3 - 4.f*a[4] - s2;
        #pragma unroll
        for (int i = 0; i < 5; ++i) {
            float y0 = w[7 + i], y1 = w[8 + i];
            K[i] = (f32x4){y0,
                           (y1 - y0) - (2.f*a[i] + a[i+1]) * (1.f/6.f),
                           0.5f * a[i],
                           (a[i+1] - a[i]) * (1.f/6.f)};
        }
    } else {
        // ---- slow (~6 threads/row): reflected-RHS, global reads ----
        float M1g  = xr[0]   - 2.f*xr[1]   + xr[2];
        float Mn2g = xr[W-1] - 2.f*xr[W-2] + xr[W-3];
        float Y[6], Mv[6];
        #pragma unroll
        for (int d = 0; d < 6; ++d) {
            int j = A - 1 + d;
            j = j < 0 ? 0 : (j > W - 1 ? W - 1 : j);
            Y[d] = xr[j];
            float m;
            if (j == 0)        m = 2.f*M1g  - convg(xr, 2,   M1g, Mn2g);
            else if (j == 1)   m = M1g;
            else if (j == W-2) m = Mn2g;
            else if (j == W-1) m = 2.f*Mn2g - convg(xr, W-3, M1g, Mn2g);
            else               m = convg(xr, j, M1g, Mn2g);
            Mv[d] = m;
        }
        #pragma unroll
        for (int i = 0; i < 5; ++i) {
            K[i] = (f32x4){Y[i],
                           (Y[i+1] - Y[i]) - (2.f*Mv[i] + Mv[i+1]) * (1.f/6.f),
                           0.5f * Mv[i],
                           (Mv[i+1] - Mv[i]) * (1.f/6.f)};
        }
    }

    // ---- eval: 4 quads, exact integer t (R12-proven); dense stores ----
    constexpr float inv = 1.f / 32767.f;
    const int e0 = 32767 - 3 * A;
    #pragma unroll
    for (int c = 0; c < 4; ++c) {
        const int e = e0 - 3 * c;             // quad h = A+c
        f32x4 cA = K[c], cB = K[c + 1];
        const int N1 = e + 8191, N2 = e + 16382;
        const bool c1 = N1 >= 32767, c2 = N2 >= 32767;
        float t0 = (float)e * inv;
        float t1 = (float)(c1 ? N1 - 32767 : N1) * inv;
        float t2 = (float)(c2 ? N2 - 32767 : N2) * inv;
        float t3 = (float)(e - 8194) * inv;   // u=3 always crosses
        f32x4 k1 = c1 ? cB : cA;
        f32x4 k2 = c2 ? cB : cA;
        float r0 = cA.x + t0 * (cA.y + t0 * (cA.z + t0 * cA.w));
        float r1 = k1.x + t1 * (k1.y + t1 * (k1.z + t1 * k1.w));
        float r2 = k2.x + t2 * (k2.y + t2 * (k2.z + t2 * k2.w));
        float r3 = cB.x + t3 * (cB.y + t3 * (cB.z + t3 * cB.w));
        *(f32x4*)(orow + 4 * (A + c)) = (f32x4){r0, r1, r2, r3};
    }
}

extern "C" void kernel_launch(void* const* d_in, const int* in_sizes, int n_in,
                              void* d_out, int out_size, void* d_ws, size_t ws_size,
                              hipStream_t stream) {
    const float* x = (const float*)d_in[0];
    float* out = (float*)d_out;
    const int B = in_sizes[0] / W;            // 512 rows
    dim3 grid(B * 8), block(256);             // 4096 blocks, 1 row-octant each
    hipLaunchKernelGGL(spline_kernel, grid, block, 0, stream, x, out);
}